// Round 1
// baseline (872.107 us; speedup 1.0000x reference)
//
#include <hip/hip_runtime.h>
#include <hip/hip_bf16.h>
#include <stdint.h>

// Problem constants
#define B_   4
#define T_   1024
#define D_   1024
#define E_   8
#define FF_  2048
#define NT_  4096            // B*T tokens
#define LCAP 9216            // 8192 pairs + 8*128 tile padding headroom

typedef unsigned short u16;
typedef __attribute__((ext_vector_type(8))) short bf16x8;   // 8 bf16 = 4 VGPRs
typedef __attribute__((ext_vector_type(4))) float f32x4;

#define MFMA16(a, b, c) __builtin_amdgcn_mfma_f32_16x16x32_bf16((a), (b), (c), 0, 0, 0)

__device__ __forceinline__ u16 f2bf(float f) {
  union { float f; uint32_t u; } c; c.f = f;
  return (u16)((c.u + 0x7FFFu + ((c.u >> 16) & 1u)) >> 16);   // RNE
}

__device__ __forceinline__ void gl_lds16(const void* g, void* l) {
  __builtin_amdgcn_global_load_lds(
      (const __attribute__((address_space(1))) uint32_t*)g,
      (__attribute__((address_space(3))) uint32_t*)l, 16, 0, 0);
}

// ---------------- small kernels ----------------

__global__ __launch_bounds__(256) void k_init(int* __restrict__ tok, float* __restrict__ gate,
                                              int* __restrict__ cnt, int* __restrict__ cur) {
  int i = blockIdx.x * 256 + threadIdx.x;
  if (i < LCAP) { tok[i] = 0; gate[i] = 0.f; }
  if (i < E_)   { cnt[i] = 0; cur[i] = 0; }
}

// out = x (f32 copy) and xb = bf16(x), one pass over x
__global__ __launch_bounds__(256) void k_prep(const float4* __restrict__ x4,
                                              float4* __restrict__ out4,
                                              ushort4* __restrict__ xb4) {
  int i = blockIdx.x * 256 + threadIdx.x;   // exactly NT_*D_/4 threads
  float4 v = x4[i];
  out4[i] = v;
  ushort4 o; o.x = f2bf(v.x); o.y = f2bf(v.y); o.z = f2bf(v.z); o.w = f2bf(v.w);
  xb4[i] = o;
}

// one wave per token: 8 dot products of length 1024
__global__ __launch_bounds__(256) void k_router(const float* __restrict__ x,
                                                const float* __restrict__ rw,
                                                const float* __restrict__ rb,
                                                const float* __restrict__ temp,
                                                float* __restrict__ scores) {
  int wid  = (blockIdx.x * 256 + threadIdx.x) >> 6;   // token id, grid = 1024 blocks
  int lane = threadIdx.x & 63;
  const float* xr = x + (size_t)wid * D_;
  float acc[E_];
  #pragma unroll
  for (int e = 0; e < E_; ++e) acc[e] = 0.f;
  for (int i = lane; i < D_; i += 64) {
    float xv = xr[i];
    #pragma unroll
    for (int e = 0; e < E_; ++e) acc[e] += xv * rw[e * D_ + i];
  }
  float inv = 1.0f / fmaxf(temp[0], 0.1f);
  #pragma unroll
  for (int e = 0; e < E_; ++e) {
    float v = acc[e];
    for (int off = 32; off; off >>= 1) v += __shfl_xor(v, off);
    if (lane == 0) scores[(size_t)wid * E_ + e] = (v + rb[e]) * inv;
  }
}

// one block per batch b; thread t owns token row [b,t]; 3 Sinkhorn iters + top-2
__global__ __launch_bounds__(1024) void k_sinkhorn(const float* __restrict__ scores,
                                                   float* __restrict__ tkg, int* __restrict__ tki,
                                                   int* __restrict__ cnt) {
  const int b = blockIdx.x, t = threadIdx.x;
  const int row = b * T_ + t;
  float s[E_];
  #pragma unroll
  for (int e = 0; e < E_; ++e) s[e] = scores[(size_t)row * E_ + e];

  __shared__ float red[16][E_];
  __shared__ int lcnt[E_];
  if (t < E_) lcnt[t] = 0;
  const int wid = t >> 6, lane = t & 63;

  for (int it = 0; it < 3; ++it) {
    // row logsumexp over E
    float m = s[0];
    #pragma unroll
    for (int e = 1; e < E_; ++e) m = fmaxf(m, s[e]);
    float sum = 0.f;
    #pragma unroll
    for (int e = 0; e < E_; ++e) sum += expf(s[e] - m);
    float lse = m + logf(sum);
    #pragma unroll
    for (int e = 0; e < E_; ++e) s[e] -= lse;

    // column max over T (1024 threads)
    float cm[E_];
    #pragma unroll
    for (int e = 0; e < E_; ++e) {
      float v = s[e];
      for (int off = 32; off; off >>= 1) v = fmaxf(v, __shfl_xor(v, off));
      if (lane == 0) red[wid][e] = v;
    }
    __syncthreads();
    #pragma unroll
    for (int e = 0; e < E_; ++e) {
      float mm = red[0][e];
      for (int wv = 1; wv < 16; ++wv) mm = fmaxf(mm, red[wv][e]);
      cm[e] = mm;
    }
    __syncthreads();
    // column sum of exp
    #pragma unroll
    for (int e = 0; e < E_; ++e) {
      float v = expf(s[e] - cm[e]);
      for (int off = 32; off; off >>= 1) v += __shfl_xor(v, off);
      if (lane == 0) red[wid][e] = v;
    }
    __syncthreads();
    #pragma unroll
    for (int e = 0; e < E_; ++e) {
      float ss = 0.f;
      for (int wv = 0; wv < 16; ++wv) ss += red[wv][e];
      s[e] -= cm[e] + logf(ss);
    }
    __syncthreads();
  }

  float g[E_]; float rs = 0.f;
  #pragma unroll
  for (int e = 0; e < E_; ++e) { g[e] = expf(s[e]); rs += g[e]; }
  float inv = 1.f / (rs + 1e-8f);
  #pragma unroll
  for (int e = 0; e < E_; ++e) g[e] *= inv;

  int i0 = 0; float v0 = g[0];
  #pragma unroll
  for (int e = 1; e < E_; ++e) if (g[e] > v0) { v0 = g[e]; i0 = e; }
  int i1 = -1; float v1 = -1e30f;
  #pragma unroll
  for (int e = 0; e < E_; ++e) if (e != i0 && g[e] > v1) { v1 = g[e]; i1 = e; }
  float den = 1.f / (v0 + v1 + 1e-8f);
  tkg[row * 2 + 0] = v0 * den; tki[row * 2 + 0] = i0;
  tkg[row * 2 + 1] = v1 * den; tki[row * 2 + 1] = i1;

  atomicAdd(&lcnt[i0], 1);
  atomicAdd(&lcnt[i1], 1);
  __syncthreads();
  if (t < E_) atomicAdd(&cnt[t], lcnt[t]);
}

__global__ void k_offsets(const int* __restrict__ cnt, int* __restrict__ segoff) {
  if (threadIdx.x == 0 && blockIdx.x == 0) {
    int run = 0;
    for (int e = 0; e < E_; ++e) { segoff[e] = run; run += ((cnt[e] + 127) >> 7) << 7; }
  }
}

__global__ __launch_bounds__(256) void k_scatter(const int* __restrict__ tki, const float* __restrict__ tkg,
                                                 const int* __restrict__ segoff, int* __restrict__ cur,
                                                 int* __restrict__ tok, float* __restrict__ gate) {
  int idx = blockIdx.x * 256 + threadIdx.x;    // 8192 pairs
  int row = idx >> 1;
  int e = tki[idx];
  float g = tkg[idx];
  int pos = atomicAdd(&cur[e], 1);
  int p = segoff[e] + pos;
  tok[p] = row;
  gate[p] = g;
}

// f32 [z][R][C] -> bf16 [z][C][R]
__global__ __launch_bounds__(256) void k_transpose(const float* __restrict__ in, u16* __restrict__ out,
                                                   int R, int C) {
  __shared__ __align__(16) u16 t[32][36];
  const size_t msz = (size_t)R * C;
  const float* A = in + blockIdx.z * msz;
  u16* O = out + blockIdx.z * msz;
  const int r0 = blockIdx.y * 32, c0 = blockIdx.x * 32;
  const int tid = threadIdx.x;
  {
    const int i = tid >> 3, j4 = (tid & 7) << 2;
    const float4 v = *(const float4*)(A + (size_t)(r0 + i) * C + c0 + j4);
    ushort4 pk; pk.x = f2bf(v.x); pk.y = f2bf(v.y); pk.z = f2bf(v.z); pk.w = f2bf(v.w);
    *(ushort4*)(&t[i][j4]) = pk;
  }
  __syncthreads();
  {
    const int j2 = tid & 15;
    #pragma unroll
    for (int it = 0; it < 2; ++it) {
      const int r = (tid >> 4) + it * 16;
      uint32_t pv = (uint32_t)t[2 * j2][r] | ((uint32_t)t[2 * j2 + 1][r] << 16);
      *(uint32_t*)(O + (size_t)(c0 + r) * R + r0 + 2 * j2) = pv;
    }
  }
}

// ---------------- grouped GEMM stage 1: H = relu(X wg) * (X wp), bf16 ----------------
// grid: x = pair-tile (128 pairs), y = FF tile (128), z = expert. Computes H^T tiles:
// D[i=f][j=p] = sum_d wgT[f][d] * xb[p][d]  (both operands K(d)-contiguous).
__global__ __launch_bounds__(256) void k_stage1(
    const u16* __restrict__ wgT, const u16* __restrict__ wpT,
    const u16* __restrict__ xb, const int* __restrict__ tok,
    const int* __restrict__ cnt, const int* __restrict__ segoff,
    u16* __restrict__ H) {
  const int e = blockIdx.z;
  const int pt = blockIdx.x;
  const int n = cnt[e];
  if (pt * 128 >= n) return;
  const int ft = blockIdx.y;
  const int tid = threadIdx.x;
  const int lane = tid & 63;
  const int w = tid >> 6;

  __shared__ __align__(16) u16 lg[128 * 32];
  __shared__ __align__(16) u16 lp[128 * 32];
  __shared__ __align__(16) u16 lx[128 * 32];

  const int prow0 = segoff[e] + pt * 128;
  const int srow = lane >> 2;
  const int scol = (lane & 3) * 8;

  const size_t wbase = (size_t)e * FF_ * D_ + (size_t)(ft * 128 + w * 32 + srow) * D_ + scol;
  const u16* gsrc = wgT + wbase;
  const u16* psrc = wpT + wbase;
  const int tk0 = tok[prow0 + w * 32 + srow];
  const int tk1 = tok[prow0 + w * 32 + 16 + srow];
  const u16* xsrc0 = xb + (size_t)tk0 * D_ + scol;
  const u16* xsrc1 = xb + (size_t)tk1 * D_ + scol;

  u16* lgd0 = lg + (w * 32) * 32;      u16* lgd1 = lg + (w * 32 + 16) * 32;
  u16* lpd0 = lp + (w * 32) * 32;      u16* lpd1 = lp + (w * 32 + 16) * 32;
  u16* lxd0 = lx + (w * 32) * 32;      u16* lxd1 = lx + (w * 32 + 16) * 32;

  const f32x4 vz = {0.f, 0.f, 0.f, 0.f};
  f32x4 accG[4][4], accP[4][4];
  #pragma unroll
  for (int m = 0; m < 4; ++m)
    #pragma unroll
    for (int nn = 0; nn < 4; ++nn) { accG[m][nn] = vz; accP[m][nn] = vz; }

  const int wf  = (w >> 1) * 64;   // f offset of this wave's subtile
  const int wpp = (w & 1) * 64;    // p offset
  const int lrow = lane & 15;
  const int lk = (lane >> 4) * 8;

  for (int kk = 0; kk < D_ / 32; ++kk) {
    const int kc = kk * 32;
    gl_lds16(gsrc + kc, lgd0);
    gl_lds16(gsrc + 16 * D_ + kc, lgd1);
    gl_lds16(psrc + kc, lpd0);
    gl_lds16(psrc + 16 * D_ + kc, lpd1);
    gl_lds16(xsrc0 + kc, lxd0);
    gl_lds16(xsrc1 + kc, lxd1);
    __syncthreads();                 // compiler drains vmcnt before barrier
    bf16x8 ag[4], ap[4], bx[4];
    #pragma unroll
    for (int m = 0; m < 4; ++m) {
      ag[m] = *(const bf16x8*)(lg + (wf  + m * 16 + lrow) * 32 + lk);
      ap[m] = *(const bf16x8*)(lp + (wf  + m * 16 + lrow) * 32 + lk);
      bx[m] = *(const bf16x8*)(lx + (wpp + m * 16 + lrow) * 32 + lk);
    }
    #pragma unroll
    for (int m = 0; m < 4; ++m)
      #pragma unroll
      for (int nn = 0; nn < 4; ++nn) {
        accG[m][nn] = MFMA16(ag[m], bx[nn], accG[m][nn]);
        accP[m][nn] = MFMA16(ap[m], bx[nn], accP[m][nn]);
      }
    __syncthreads();
  }

  // epilogue: H[p][f], lane's 4 regs are consecutive f -> packed 8B stores
  const int jrow = (lane >> 4) * 4;
  #pragma unroll
  for (int m = 0; m < 4; ++m) {
    #pragma unroll
    for (int nn = 0; nn < 4; ++nn) {
      union { uint2 v; u16 s[4]; } u;
      #pragma unroll
      for (int j = 0; j < 4; ++j)
        u.s[j] = f2bf(fmaxf(accG[m][nn][j], 0.f) * accP[m][nn][j]);
      const int prow = prow0 + wpp + nn * 16 + lrow;
      const int fcol = ft * 128 + wf + m * 16 + jrow;
      *(uint2*)(H + (size_t)prow * FF_ + fcol) = u.v;
    }
  }
}

// ---------------- grouped GEMM stage 2: O = (H @ wo) * gate, atomic += into out ----------------
// grid: x = pair-tile, y = D tile (128), z = expert. D[i=p][j=d] = sum_ff H[p][ff]*woT[d][ff]
__global__ __launch_bounds__(256) void k_stage2(
    const u16* __restrict__ H, const u16* __restrict__ woT,
    const int* __restrict__ tok, const float* __restrict__ gate,
    const int* __restrict__ cnt, const int* __restrict__ segoff,
    float* __restrict__ out) {
  const int e = blockIdx.z;
  const int pt = blockIdx.x;
  const int n = cnt[e];
  if (pt * 128 >= n) return;
  const int dt = blockIdx.y;
  const int tid = threadIdx.x;
  const int lane = tid & 63;
  const int w = tid >> 6;

  __shared__ __align__(16) u16 lh[128 * 32];
  __shared__ __align__(16) u16 lw[128 * 32];
  __shared__ int   ltok[128];
  __shared__ float lgt[128];

  const int prow0 = segoff[e] + pt * 128;
  if (tid < 128) { ltok[tid] = tok[prow0 + tid]; lgt[tid] = gate[prow0 + tid]; }

  const int srow = lane >> 2;
  const int scol = (lane & 3) * 8;

  const u16* hsrc = H + (size_t)(prow0 + w * 32 + srow) * FF_ + scol;
  const u16* wsrc = woT + (size_t)e * D_ * FF_ + (size_t)(dt * 128 + w * 32 + srow) * FF_ + scol;

  u16* lhd0 = lh + (w * 32) * 32;   u16* lhd1 = lh + (w * 32 + 16) * 32;
  u16* lwd0 = lw + (w * 32) * 32;   u16* lwd1 = lw + (w * 32 + 16) * 32;

  const f32x4 vz = {0.f, 0.f, 0.f, 0.f};
  f32x4 acc[4][4];
  #pragma unroll
  for (int m = 0; m < 4; ++m)
    #pragma unroll
    for (int nn = 0; nn < 4; ++nn) acc[m][nn] = vz;

  const int wpp = (w & 1) * 64;    // p offset
  const int wd  = (w >> 1) * 64;   // d offset
  const int lrow = lane & 15;
  const int lk = (lane >> 4) * 8;

  for (int kk = 0; kk < FF_ / 32; ++kk) {
    const int kc = kk * 32;
    gl_lds16(hsrc + kc, lhd0);
    gl_lds16(hsrc + 16 * FF_ + kc, lhd1);
    gl_lds16(wsrc + kc, lwd0);
    gl_lds16(wsrc + 16 * FF_ + kc, lwd1);
    __syncthreads();
    bf16x8 ah[4], bw[4];
    #pragma unroll
    for (int m = 0; m < 4; ++m) {
      ah[m] = *(const bf16x8*)(lh + (wpp + m * 16 + lrow) * 32 + lk);
      bw[m] = *(const bf16x8*)(lw + (wd  + m * 16 + lrow) * 32 + lk);
    }
    #pragma unroll
    for (int m = 0; m < 4; ++m)
      #pragma unroll
      for (int nn = 0; nn < 4; ++nn)
        acc[m][nn] = MFMA16(ah[m], bw[nn], acc[m][nn]);
    __syncthreads();
  }

  const int jrow = (lane >> 4) * 4;
  #pragma unroll
  for (int m = 0; m < 4; ++m) {
    #pragma unroll
    for (int nn = 0; nn < 4; ++nn) {
      const int dcol = dt * 128 + wd + nn * 16 + lrow;
      #pragma unroll
      for (int j = 0; j < 4; ++j) {
        const int pl = wpp + m * 16 + jrow + j;
        unsafeAtomicAdd(&out[(size_t)ltok[pl] * D_ + dcol], lgt[pl] * acc[m][nn][j]);
      }
    }
  }
}

// ---------------- host ----------------

extern "C" void kernel_launch(void* const* d_in, const int* in_sizes, int n_in,
                              void* d_out, int out_size, void* d_ws, size_t ws_size,
                              hipStream_t stream) {
  const float* x    = (const float*)d_in[0];
  const float* rw   = (const float*)d_in[1];
  const float* rb   = (const float*)d_in[2];
  const float* temp = (const float*)d_in[3];
  const float* wg   = (const float*)d_in[4];
  const float* wp   = (const float*)d_in[5];
  const float* wo   = (const float*)d_in[6];
  float* out = (float*)d_out;
  char* ws = (char*)d_ws;

  // workspace layout (bytes)
  const size_t O_XB  = 0;                                  // NT*D bf16      = 8,388,608
  const size_t O_WGT = 8388608;                            // E*FF*D bf16    = 33,554,432
  const size_t O_WPT = O_WGT + 33554432;
  const size_t O_WOT = O_WGT;                              // reuses wgT region after stage1
  const size_t O_H   = O_WPT + 33554432;                   // LCAP*FF bf16   = 37,748,736
  const size_t O_SC  = O_H + (size_t)LCAP * FF_ * 2;
  const size_t O_TKG = O_SC + (size_t)NT_ * E_ * 4;
  const size_t O_TKI = O_TKG + (size_t)NT_ * 2 * 4;
  const size_t O_CNT = O_TKI + (size_t)NT_ * 2 * 4;
  const size_t O_CUR = O_CNT + 128;
  const size_t O_SEG = O_CUR + 128;
  const size_t O_TOK = O_SEG + 128;
  const size_t O_GTE = O_TOK + (size_t)LCAP * 4;
  const size_t REQ   = O_GTE + (size_t)LCAP * 4;           // ~108.3 MB
  if (ws_size < REQ) return;   // fail visibly (poisoned d_out) rather than corrupt memory

  u16*   xb     = (u16*)(ws + O_XB);
  u16*   wgT    = (u16*)(ws + O_WGT);
  u16*   wpT    = (u16*)(ws + O_WPT);
  u16*   woT    = (u16*)(ws + O_WOT);
  u16*   Hbuf   = (u16*)(ws + O_H);
  float* scores = (float*)(ws + O_SC);
  float* tkg    = (float*)(ws + O_TKG);
  int*   tki    = (int*)(ws + O_TKI);
  int*   cnt    = (int*)(ws + O_CNT);
  int*   cur    = (int*)(ws + O_CUR);
  int*   segoff = (int*)(ws + O_SEG);
  int*   tok    = (int*)(ws + O_TOK);
  float* gate   = (float*)(ws + O_GTE);

  k_init<<<(LCAP + 255) / 256, 256, 0, stream>>>(tok, gate, cnt, cur);
  k_prep<<<(NT_ * D_ / 4) / 256, 256, 0, stream>>>((const float4*)x, (float4*)out, (ushort4*)xb);
  k_router<<<NT_ / 4, 256, 0, stream>>>(x, rw, rb, temp, scores);
  k_sinkhorn<<<B_, 1024, 0, stream>>>(scores, tkg, tki, cnt);
  k_offsets<<<1, 64, 0, stream>>>(cnt, segoff);
  k_scatter<<<(NT_ * 2) / 256, 256, 0, stream>>>(tki, tkg, segoff, cur, tok, gate);

  // weight transposes to bf16: wg,wp: [D][FF] -> [FF][D]
  k_transpose<<<dim3(FF_ / 32, D_ / 32, E_), 256, 0, stream>>>(wg, wgT, D_, FF_);
  k_transpose<<<dim3(FF_ / 32, D_ / 32, E_), 256, 0, stream>>>(wp, wpT, D_, FF_);

  k_stage1<<<dim3(64, FF_ / 128, E_), 256, 0, stream>>>(wgT, wpT, xb, tok, cnt, segoff, Hbuf);

  // wo: [FF][D] -> [D][FF]  (overwrites wgT region, dead after stage1)
  k_transpose<<<dim3(D_ / 32, FF_ / 32, E_), 256, 0, stream>>>(wo, woT, FF_, D_);

  k_stage2<<<dim3(64, D_ / 128, E_), 256, 0, stream>>>(Hbuf, woT, tok, gate, cnt, segoff, out);
}

// Round 2
// 573.091 us; speedup vs baseline: 1.5218x; 1.5218x over previous
//
#include <hip/hip_runtime.h>
#include <hip/hip_bf16.h>
#include <stdint.h>

// Problem constants
#define B_   4
#define T_   1024
#define D_   1024
#define E_   8
#define FF_  2048
#define NT_  4096            // B*T tokens
#define LCAP 9216            // 8192 pairs + 8*128 tile padding headroom

typedef unsigned short u16;
typedef __attribute__((ext_vector_type(8))) short bf16x8;   // 8 bf16 = 4 VGPRs
typedef __attribute__((ext_vector_type(4))) float f32x4;

#define MFMA16(a, b, c) __builtin_amdgcn_mfma_f32_16x16x32_bf16((a), (b), (c), 0, 0, 0)

__device__ __forceinline__ u16 f2bf(float f) {
  union { float f; uint32_t u; } c; c.f = f;
  return (u16)((c.u + 0x7FFFu + ((c.u >> 16) & 1u)) >> 16);   // RNE
}

__device__ __forceinline__ void gl_lds16(const void* g, void* l) {
  __builtin_amdgcn_global_load_lds(
      (const __attribute__((address_space(1))) uint32_t*)g,
      (__attribute__((address_space(3))) uint32_t*)l, 16, 0, 0);
}

// ---------------- small kernels ----------------

__global__ __launch_bounds__(256) void k_init(int* __restrict__ tok, float* __restrict__ gate,
                                              int* __restrict__ cnt, int* __restrict__ cur) {
  int i = blockIdx.x * 256 + threadIdx.x;
  if (i < LCAP) { tok[i] = 0; gate[i] = 0.f; }
  if (i < E_)   { cnt[i] = 0; cur[i] = 0; }
}

// out = x (f32 copy) and xb = bf16(x), one pass over x
__global__ __launch_bounds__(256) void k_prep(const float4* __restrict__ x4,
                                              float4* __restrict__ out4,
                                              ushort4* __restrict__ xb4) {
  int i = blockIdx.x * 256 + threadIdx.x;   // exactly NT_*D_/4 threads
  float4 v = x4[i];
  out4[i] = v;
  ushort4 o; o.x = f2bf(v.x); o.y = f2bf(v.y); o.z = f2bf(v.z); o.w = f2bf(v.w);
  xb4[i] = o;
}

// one wave per token: 8 dot products of length 1024
__global__ __launch_bounds__(256) void k_router(const float* __restrict__ x,
                                                const float* __restrict__ rw,
                                                const float* __restrict__ rb,
                                                const float* __restrict__ temp,
                                                float* __restrict__ scores) {
  int wid  = (blockIdx.x * 256 + threadIdx.x) >> 6;   // token id
  int lane = threadIdx.x & 63;
  const float* xr = x + (size_t)wid * D_;
  float acc[E_];
  #pragma unroll
  for (int e = 0; e < E_; ++e) acc[e] = 0.f;
  for (int i = lane; i < D_; i += 64) {
    float xv = xr[i];
    #pragma unroll
    for (int e = 0; e < E_; ++e) acc[e] += xv * rw[e * D_ + i];
  }
  float inv = 1.0f / fmaxf(temp[0], 0.1f);
  #pragma unroll
  for (int e = 0; e < E_; ++e) {
    float v = acc[e];
    for (int off = 32; off; off >>= 1) v += __shfl_xor(v, off);
    if (lane == 0) scores[(size_t)wid * E_ + e] = (v + rb[e]) * inv;
  }
}

// one block per batch b; thread t owns token row [b,t]; 3 Sinkhorn iters + top-2
__global__ __launch_bounds__(1024) void k_sinkhorn(const float* __restrict__ scores,
                                                   float* __restrict__ tkg, int* __restrict__ tki,
                                                   int* __restrict__ cnt) {
  const int b = blockIdx.x, t = threadIdx.x;
  const int row = b * T_ + t;
  float s[E_];
  #pragma unroll
  for (int e = 0; e < E_; ++e) s[e] = scores[(size_t)row * E_ + e];

  __shared__ float red[16][E_];
  __shared__ int lcnt[E_];
  if (t < E_) lcnt[t] = 0;
  const int wid = t >> 6, lane = t & 63;

  for (int it = 0; it < 3; ++it) {
    float m = s[0];
    #pragma unroll
    for (int e = 1; e < E_; ++e) m = fmaxf(m, s[e]);
    float sum = 0.f;
    #pragma unroll
    for (int e = 0; e < E_; ++e) sum += expf(s[e] - m);
    float lse = m + logf(sum);
    #pragma unroll
    for (int e = 0; e < E_; ++e) s[e] -= lse;

    float cm[E_];
    #pragma unroll
    for (int e = 0; e < E_; ++e) {
      float v = s[e];
      for (int off = 32; off; off >>= 1) v = fmaxf(v, __shfl_xor(v, off));
      if (lane == 0) red[wid][e] = v;
    }
    __syncthreads();
    #pragma unroll
    for (int e = 0; e < E_; ++e) {
      float mm = red[0][e];
      for (int wv = 1; wv < 16; ++wv) mm = fmaxf(mm, red[wv][e]);
      cm[e] = mm;
    }
    __syncthreads();
    #pragma unroll
    for (int e = 0; e < E_; ++e) {
      float v = expf(s[e] - cm[e]);
      for (int off = 32; off; off >>= 1) v += __shfl_xor(v, off);
      if (lane == 0) red[wid][e] = v;
    }
    __syncthreads();
    #pragma unroll
    for (int e = 0; e < E_; ++e) {
      float ss = 0.f;
      for (int wv = 0; wv < 16; ++wv) ss += red[wv][e];
      s[e] -= cm[e] + logf(ss);
    }
    __syncthreads();
  }

  float g[E_]; float rs = 0.f;
  #pragma unroll
  for (int e = 0; e < E_; ++e) { g[e] = expf(s[e]); rs += g[e]; }
  float inv = 1.f / (rs + 1e-8f);
  #pragma unroll
  for (int e = 0; e < E_; ++e) g[e] *= inv;

  int i0 = 0; float v0 = g[0];
  #pragma unroll
  for (int e = 1; e < E_; ++e) if (g[e] > v0) { v0 = g[e]; i0 = e; }
  int i1 = -1; float v1 = -1e30f;
  #pragma unroll
  for (int e = 0; e < E_; ++e) if (e != i0 && g[e] > v1) { v1 = g[e]; i1 = e; }
  float den = 1.f / (v0 + v1 + 1e-8f);
  tkg[row * 2 + 0] = v0 * den; tki[row * 2 + 0] = i0;
  tkg[row * 2 + 1] = v1 * den; tki[row * 2 + 1] = i1;

  atomicAdd(&lcnt[i0], 1);
  atomicAdd(&lcnt[i1], 1);
  __syncthreads();
  if (t < E_) atomicAdd(&cnt[t], lcnt[t]);
}

__global__ void k_offsets(const int* __restrict__ cnt, int* __restrict__ segoff) {
  if (threadIdx.x == 0 && blockIdx.x == 0) {
    int run = 0;
    for (int e = 0; e < E_; ++e) { segoff[e] = run; run += ((cnt[e] + 127) >> 7) << 7; }
  }
}

__global__ __launch_bounds__(256) void k_scatter(const int* __restrict__ tki, const float* __restrict__ tkg,
                                                 const int* __restrict__ segoff, int* __restrict__ cur,
                                                 int* __restrict__ tok, float* __restrict__ gate) {
  int idx = blockIdx.x * 256 + threadIdx.x;    // 8192 pairs
  int row = idx >> 1;
  int e = tki[idx];
  float g = tkg[idx];
  int pos = atomicAdd(&cur[e], 1);
  int p = segoff[e] + pos;
  tok[p] = row;
  gate[p] = g;
}

// f32 [z][R][C] -> bf16 [z][C][R]
__global__ __launch_bounds__(256) void k_transpose(const float* __restrict__ in, u16* __restrict__ out,
                                                   int R, int C) {
  __shared__ __align__(16) u16 t[32][36];
  const size_t msz = (size_t)R * C;
  const float* A = in + blockIdx.z * msz;
  u16* O = out + blockIdx.z * msz;
  const int r0 = blockIdx.y * 32, c0 = blockIdx.x * 32;
  const int tid = threadIdx.x;
  {
    const int i = tid >> 3, j4 = (tid & 7) << 2;
    const float4 v = *(const float4*)(A + (size_t)(r0 + i) * C + c0 + j4);
    ushort4 pk; pk.x = f2bf(v.x); pk.y = f2bf(v.y); pk.z = f2bf(v.z); pk.w = f2bf(v.w);
    *(ushort4*)(&t[i][j4]) = pk;
  }
  __syncthreads();
  {
    const int j2 = tid & 15;
    #pragma unroll
    for (int it = 0; it < 2; ++it) {
      const int r = (tid >> 4) + it * 16;
      uint32_t pv = (uint32_t)t[2 * j2][r] | ((uint32_t)t[2 * j2 + 1][r] << 16);
      *(uint32_t*)(O + (size_t)(c0 + r) * R + r0 + 2 * j2) = pv;
    }
  }
}

// ---- shared GEMM helpers: chunk-major 16-row-block LDS layout ----
// Tile = 128 rows x 32 k (bf16). 8 row-blocks of 1KB. Within a row-block:
// [4 kchunks][16 rows][8 u16]. Fragment read for rows R0+ (lane&15), kchunk
// (lane>>4) = base + rowblock*512 + lane*8 u16 -> single linear ds_read_b128,
// zero bank conflicts. gl_lds16 writes lane i at +16i bytes, so the global
// source for lane i is row (i&15), kchunk (i>>4) -> same 64B segments as the
// naive order, just permuted across lanes.

__device__ __forceinline__ void mm_step2op(const u16* ba, const u16* bb,
                                           int ab0, int bb0, int lane8,
                                           f32x4 acc[4][4]) {
  bf16x8 av[4], bv[4];
  #pragma unroll
  for (int m = 0; m < 4; ++m) {
    av[m] = *(const bf16x8*)(ba + (ab0 + m) * 512 + lane8);
    bv[m] = *(const bf16x8*)(bb + (bb0 + m) * 512 + lane8);
  }
  #pragma unroll
  for (int m = 0; m < 4; ++m)
    #pragma unroll
    for (int nn = 0; nn < 4; ++nn)
      acc[m][nn] = MFMA16(av[m], bv[nn], acc[m][nn]);
}

__device__ __forceinline__ void mm_step3op(const u16* bg, const u16* bp, const u16* bx_,
                                           int fb0, int pb0, int lane8,
                                           f32x4 accG[4][4], f32x4 accP[4][4]) {
  bf16x8 ag[4], ap[4], bxv[4];
  #pragma unroll
  for (int m = 0; m < 4; ++m) {
    ag[m]  = *(const bf16x8*)(bg + (fb0 + m) * 512 + lane8);
    ap[m]  = *(const bf16x8*)(bp + (fb0 + m) * 512 + lane8);
    bxv[m] = *(const bf16x8*)(bx_ + (pb0 + m) * 512 + lane8);
  }
  #pragma unroll
  for (int m = 0; m < 4; ++m)
    #pragma unroll
    for (int nn = 0; nn < 4; ++nn) {
      accG[m][nn] = MFMA16(ag[m], bxv[nn], accG[m][nn]);
      accP[m][nn] = MFMA16(ap[m], bxv[nn], accP[m][nn]);
    }
}

// ---------------- grouped GEMM stage 1: H = relu(X wg) * (X wp), bf16 ----------------
// 1-D grid 4096 = 32 pt x 16 ft x 8 e. e = raw%8 pins each expert to one XCD
// (round-robin dispatch assumption; perf-only). pt fastest within ft so the
// active pair-tile blocks of one ft share the weight tile in that XCD's L2.
__global__ __launch_bounds__(256) void k_stage1(
    const u16* __restrict__ wgT, const u16* __restrict__ wpT,
    const u16* __restrict__ xb, const int* __restrict__ tok,
    const int* __restrict__ cnt, const int* __restrict__ segoff,
    u16* __restrict__ H) {
  const int raw = blockIdx.x;
  const int e  = raw & 7;
  const int rem = raw >> 3;          // 0..511
  const int ft = rem >> 5;           // 0..15
  const int pt = rem & 31;           // 0..31
  const int n = cnt[e];
  if (pt * 128 >= n) return;
  const int tid = threadIdx.x;
  const int lane = tid & 63;
  const int w = tid >> 6;

  __shared__ __align__(16) u16 lgA[4096], lgB[4096];
  __shared__ __align__(16) u16 lpA[4096], lpB[4096];
  __shared__ __align__(16) u16 lxA[4096], lxB[4096];

  const int prow0 = segoff[e] + pt * 128;
  const int lane15 = lane & 15;
  const int lchunk = lane >> 4;
  const int lane8 = lane * 8;
  const int rbo = w * 1024;           // this wave's 2 row-blocks start (u16 units)

  const size_t wbase = (size_t)e * FF_ * D_ + (size_t)(ft * 128 + w * 32 + lane15) * D_ + lchunk * 8;
  const u16* gp0 = wgT + wbase;  const u16* gp1 = gp0 + 16 * D_;
  const u16* pp0 = wpT + wbase;  const u16* pp1 = pp0 + 16 * D_;
  const int tk0 = tok[prow0 + w * 32 + lane15];
  const int tk1 = tok[prow0 + w * 32 + 16 + lane15];
  const u16* xp0 = xb + (size_t)tk0 * D_ + lchunk * 8;
  const u16* xp1 = xb + (size_t)tk1 * D_ + lchunk * 8;

  const f32x4 vz = {0.f, 0.f, 0.f, 0.f};
  f32x4 accG[4][4], accP[4][4];
  #pragma unroll
  for (int m = 0; m < 4; ++m)
    #pragma unroll
    for (int nn = 0; nn < 4; ++nn) { accG[m][nn] = vz; accP[m][nn] = vz; }

  const int fb0 = (w >> 1) * 4;   // f row-block base of this wave's subtile
  const int pb0 = (w & 1) * 4;    // p row-block base
  const int wf  = (w >> 1) * 64;
  const int wpp = (w & 1) * 64;

#define STG1(BG, BP, BX, KC) do { int kc_ = (KC);            \
    gl_lds16(gp0 + kc_, BG + rbo);                           \
    gl_lds16(gp1 + kc_, BG + rbo + 512);                     \
    gl_lds16(pp0 + kc_, BP + rbo);                           \
    gl_lds16(pp1 + kc_, BP + rbo + 512);                     \
    gl_lds16(xp0 + kc_, BX + rbo);                           \
    gl_lds16(xp1 + kc_, BX + rbo + 512); } while (0)

  STG1(lgA, lpA, lxA, 0);
  int t = 0;
  #pragma unroll 1
  for (; t < D_ / 32 - 2; t += 2) {
    __syncthreads();                       // A staged; prior B-reads done
    STG1(lgB, lpB, lxB, (t + 1) * 32);     // prefetch t+1 while computing t
    mm_step3op(lgA, lpA, lxA, fb0, pb0, lane8, accG, accP);
    __syncthreads();                       // B staged; A-reads done
    STG1(lgA, lpA, lxA, (t + 2) * 32);
    mm_step3op(lgB, lpB, lxB, fb0, pb0, lane8, accG, accP);
  }
  __syncthreads();
  STG1(lgB, lpB, lxB, (t + 1) * 32);
  mm_step3op(lgA, lpA, lxA, fb0, pb0, lane8, accG, accP);
  __syncthreads();
  mm_step3op(lgB, lpB, lxB, fb0, pb0, lane8, accG, accP);
#undef STG1

  // epilogue: H[p][f], lane's 4 regs are consecutive f -> packed 8B stores
  const int jrow = (lane >> 4) * 4;
  #pragma unroll
  for (int m = 0; m < 4; ++m) {
    #pragma unroll
    for (int nn = 0; nn < 4; ++nn) {
      union { uint2 v; u16 s[4]; } u;
      #pragma unroll
      for (int j = 0; j < 4; ++j)
        u.s[j] = f2bf(fmaxf(accG[m][nn][j], 0.f) * accP[m][nn][j]);
      const int prow = prow0 + wpp + nn * 16 + lane15;
      const int fcol = ft * 128 + wf + m * 16 + jrow;
      *(uint2*)(H + (size_t)prow * FF_ + fcol) = u.v;
    }
  }
}

// ---------------- grouped GEMM stage 2: O = (H @ wo) * gate, atomic += into out ----------------
// 1-D grid 2048 = 32 pt x 8 dt x 8 e, same XCD-pinning remap.
__global__ __launch_bounds__(256) void k_stage2(
    const u16* __restrict__ H, const u16* __restrict__ woT,
    const int* __restrict__ tok, const float* __restrict__ gate,
    const int* __restrict__ cnt, const int* __restrict__ segoff,
    float* __restrict__ out) {
  const int raw = blockIdx.x;
  const int e  = raw & 7;
  const int rem = raw >> 3;          // 0..255
  const int dt = rem >> 5;           // 0..7
  const int pt = rem & 31;           // 0..31
  const int n = cnt[e];
  if (pt * 128 >= n) return;
  const int tid = threadIdx.x;
  const int lane = tid & 63;
  const int w = tid >> 6;

  __shared__ __align__(16) u16 lhA[4096], lhB[4096];
  __shared__ __align__(16) u16 lwA[4096], lwB[4096];
  __shared__ int   ltok[128];
  __shared__ float lgt[128];

  const int prow0 = segoff[e] + pt * 128;
  if (tid < 128) { ltok[tid] = tok[prow0 + tid]; lgt[tid] = gate[prow0 + tid]; }

  const int lane15 = lane & 15;
  const int lchunk = lane >> 4;
  const int lane8 = lane * 8;
  const int rbo = w * 1024;

  const u16* hp0 = H + (size_t)(prow0 + w * 32 + lane15) * FF_ + lchunk * 8;
  const u16* hp1 = hp0 + 16 * FF_;
  const u16* wp0 = woT + (size_t)e * D_ * FF_ + (size_t)(dt * 128 + w * 32 + lane15) * FF_ + lchunk * 8;
  const u16* wp1 = wp0 + 16 * FF_;

  const f32x4 vz = {0.f, 0.f, 0.f, 0.f};
  f32x4 acc[4][4];
  #pragma unroll
  for (int m = 0; m < 4; ++m)
    #pragma unroll
    for (int nn = 0; nn < 4; ++nn) acc[m][nn] = vz;

  const int pb0 = (w & 1) * 4;    // pair row-block base (A operand)
  const int db0 = (w >> 1) * 4;   // d row-block base (B operand)
  const int wpp = (w & 1) * 64;
  const int wd  = (w >> 1) * 64;

#define STG2(BH, BW, KC) do { int kc_ = (KC);                \
    gl_lds16(hp0 + kc_, BH + rbo);                           \
    gl_lds16(hp1 + kc_, BH + rbo + 512);                     \
    gl_lds16(wp0 + kc_, BW + rbo);                           \
    gl_lds16(wp1 + kc_, BW + rbo + 512); } while (0)

  STG2(lhA, lwA, 0);
  int t = 0;
  #pragma unroll 1
  for (; t < FF_ / 32 - 2; t += 2) {
    __syncthreads();
    STG2(lhB, lwB, (t + 1) * 32);
    mm_step2op(lhA, lwA, pb0, db0, lane8, acc);
    __syncthreads();
    STG2(lhA, lwA, (t + 2) * 32);
    mm_step2op(lhB, lwB, pb0, db0, lane8, acc);
  }
  __syncthreads();
  STG2(lhB, lwB, (t + 1) * 32);
  mm_step2op(lhA, lwA, pb0, db0, lane8, acc);
  __syncthreads();
  mm_step2op(lhB, lwB, pb0, db0, lane8, acc);
#undef STG2

  const int jrow = (lane >> 4) * 4;
  #pragma unroll
  for (int m = 0; m < 4; ++m) {
    #pragma unroll
    for (int nn = 0; nn < 4; ++nn) {
      const int dcol = dt * 128 + wd + nn * 16 + lane15;
      #pragma unroll
      for (int j = 0; j < 4; ++j) {
        const int pl = wpp + m * 16 + jrow + j;
        unsafeAtomicAdd(&out[(size_t)ltok[pl] * D_ + dcol], lgt[pl] * acc[m][nn][j]);
      }
    }
  }
}

// ---------------- host ----------------

extern "C" void kernel_launch(void* const* d_in, const int* in_sizes, int n_in,
                              void* d_out, int out_size, void* d_ws, size_t ws_size,
                              hipStream_t stream) {
  const float* x    = (const float*)d_in[0];
  const float* rw   = (const float*)d_in[1];
  const float* rb   = (const float*)d_in[2];
  const float* temp = (const float*)d_in[3];
  const float* wg   = (const float*)d_in[4];
  const float* wp   = (const float*)d_in[5];
  const float* wo   = (const float*)d_in[6];
  float* out = (float*)d_out;
  char* ws = (char*)d_ws;

  // workspace layout (bytes)
  const size_t O_XB  = 0;                                  // NT*D bf16      = 8,388,608
  const size_t O_WGT = 8388608;                            // E*FF*D bf16    = 33,554,432
  const size_t O_WPT = O_WGT + 33554432;
  const size_t O_WOT = O_WGT;                              // reuses wgT region after stage1
  const size_t O_H   = O_WPT + 33554432;                   // LCAP*FF bf16   = 37,748,736
  const size_t O_SC  = O_H + (size_t)LCAP * FF_ * 2;
  const size_t O_TKG = O_SC + (size_t)NT_ * E_ * 4;
  const size_t O_TKI = O_TKG + (size_t)NT_ * 2 * 4;
  const size_t O_CNT = O_TKI + (size_t)NT_ * 2 * 4;
  const size_t O_CUR = O_CNT + 128;
  const size_t O_SEG = O_CUR + 128;
  const size_t O_TOK = O_SEG + 128;
  const size_t O_GTE = O_TOK + (size_t)LCAP * 4;
  const size_t REQ   = O_GTE + (size_t)LCAP * 4;           // ~108.3 MB
  if (ws_size < REQ) return;

  u16*   xb     = (u16*)(ws + O_XB);
  u16*   wgT    = (u16*)(ws + O_WGT);
  u16*   wpT    = (u16*)(ws + O_WPT);
  u16*   woT    = (u16*)(ws + O_WOT);
  u16*   Hbuf   = (u16*)(ws + O_H);
  float* scores = (float*)(ws + O_SC);
  float* tkg    = (float*)(ws + O_TKG);
  int*   tki    = (int*)(ws + O_TKI);
  int*   cnt    = (int*)(ws + O_CNT);
  int*   cur    = (int*)(ws + O_CUR);
  int*   segoff = (int*)(ws + O_SEG);
  int*   tok    = (int*)(ws + O_TOK);
  float* gate   = (float*)(ws + O_GTE);

  k_init<<<(LCAP + 255) / 256, 256, 0, stream>>>(tok, gate, cnt, cur);
  k_prep<<<(NT_ * D_ / 4) / 256, 256, 0, stream>>>((const float4*)x, (float4*)out, (ushort4*)xb);
  k_router<<<NT_ / 4, 256, 0, stream>>>(x, rw, rb, temp, scores);
  k_sinkhorn<<<B_, 1024, 0, stream>>>(scores, tkg, tki, cnt);
  k_offsets<<<1, 64, 0, stream>>>(cnt, segoff);
  k_scatter<<<(NT_ * 2) / 256, 256, 0, stream>>>(tki, tkg, segoff, cur, tok, gate);

  // weight transposes to bf16: wg,wp: [D][FF] -> [FF][D]
  k_transpose<<<dim3(FF_ / 32, D_ / 32, E_), 256, 0, stream>>>(wg, wgT, D_, FF_);
  k_transpose<<<dim3(FF_ / 32, D_ / 32, E_), 256, 0, stream>>>(wp, wpT, D_, FF_);

  k_stage1<<<32 * 16 * E_, 256, 0, stream>>>(wgT, wpT, xb, tok, cnt, segoff, Hbuf);

  // wo: [FF][D] -> [D][FF]  (overwrites wgT region, dead after stage1)
  k_transpose<<<dim3(D_ / 32, FF_ / 32, E_), 256, 0, stream>>>(wo, woT, FF_, D_);

  k_stage2<<<32 * 8 * E_, 256, 0, stream>>>(Hbuf, woT, tok, gate, cnt, segoff, out);
}

// Round 3
// 540.544 us; speedup vs baseline: 1.6134x; 1.0602x over previous
//
#include <hip/hip_runtime.h>
#include <hip/hip_bf16.h>
#include <stdint.h>

// Problem constants
#define B_   4
#define T_   1024
#define D_   1024
#define E_   8
#define FF_  2048
#define NT_  4096            // B*T tokens
#define LCAP 9216            // 8192 pairs + 8*128 tile padding headroom
#define NT1  (D_ / 64)       // 16 K-tiles, stage1
#define NT2  (FF_ / 64)      // 32 K-tiles, stage2

typedef unsigned short u16;
typedef __attribute__((ext_vector_type(8))) short bf16x8;   // 8 bf16 = 4 VGPRs
typedef __attribute__((ext_vector_type(4))) float f32x4;

#define MFMA16(a, b, c) __builtin_amdgcn_mfma_f32_16x16x32_bf16((a), (b), (c), 0, 0, 0)

__device__ __forceinline__ u16 f2bf(float f) {
  union { float f; uint32_t u; } c; c.f = f;
  return (u16)((c.u + 0x7FFFu + ((c.u >> 16) & 1u)) >> 16);   // RNE
}

__device__ __forceinline__ void gl_lds16(const void* g, void* l) {
  __builtin_amdgcn_global_load_lds(
      (const __attribute__((address_space(1))) uint32_t*)g,
      (__attribute__((address_space(3))) uint32_t*)l, 16, 0, 0);
}

// ---------------- small kernels ----------------

__global__ __launch_bounds__(256) void k_init(int* __restrict__ tok, float* __restrict__ gate,
                                              int* __restrict__ cnt, int* __restrict__ cur) {
  int i = blockIdx.x * 256 + threadIdx.x;
  if (i < LCAP) { tok[i] = 0; gate[i] = 0.f; }
  if (i < E_)   { cnt[i] = 0; cur[i] = 0; }
}

// out = x (f32 copy) and xb = bf16(x), one pass over x
__global__ __launch_bounds__(256) void k_prep(const float4* __restrict__ x4,
                                              float4* __restrict__ out4,
                                              ushort4* __restrict__ xb4) {
  int i = blockIdx.x * 256 + threadIdx.x;   // exactly NT_*D_/4 threads
  float4 v = x4[i];
  out4[i] = v;
  ushort4 o; o.x = f2bf(v.x); o.y = f2bf(v.y); o.z = f2bf(v.z); o.w = f2bf(v.w);
  xb4[i] = o;
}

// one wave per token: 8 dot products of length 1024
__global__ __launch_bounds__(256) void k_router(const float* __restrict__ x,
                                                const float* __restrict__ rw,
                                                const float* __restrict__ rb,
                                                const float* __restrict__ temp,
                                                float* __restrict__ scores) {
  int wid  = (blockIdx.x * 256 + threadIdx.x) >> 6;   // token id
  int lane = threadIdx.x & 63;
  const float* xr = x + (size_t)wid * D_;
  float acc[E_];
  #pragma unroll
  for (int e = 0; e < E_; ++e) acc[e] = 0.f;
  for (int i = lane; i < D_; i += 64) {
    float xv = xr[i];
    #pragma unroll
    for (int e = 0; e < E_; ++e) acc[e] += xv * rw[e * D_ + i];
  }
  float inv = 1.0f / fmaxf(temp[0], 0.1f);
  #pragma unroll
  for (int e = 0; e < E_; ++e) {
    float v = acc[e];
    for (int off = 32; off; off >>= 1) v += __shfl_xor(v, off);
    if (lane == 0) scores[(size_t)wid * E_ + e] = (v + rb[e]) * inv;
  }
}

// one block per batch b; thread t owns token row [b,t]; 3 Sinkhorn iters + top-2
__global__ __launch_bounds__(1024) void k_sinkhorn(const float* __restrict__ scores,
                                                   float* __restrict__ tkg, int* __restrict__ tki,
                                                   int* __restrict__ cnt) {
  const int b = blockIdx.x, t = threadIdx.x;
  const int row = b * T_ + t;
  float s[E_];
  #pragma unroll
  for (int e = 0; e < E_; ++e) s[e] = scores[(size_t)row * E_ + e];

  __shared__ float red[16][E_];
  __shared__ int lcnt[E_];
  if (t < E_) lcnt[t] = 0;
  const int wid = t >> 6, lane = t & 63;

  for (int it = 0; it < 3; ++it) {
    float m = s[0];
    #pragma unroll
    for (int e = 1; e < E_; ++e) m = fmaxf(m, s[e]);
    float sum = 0.f;
    #pragma unroll
    for (int e = 0; e < E_; ++e) sum += expf(s[e] - m);
    float lse = m + logf(sum);
    #pragma unroll
    for (int e = 0; e < E_; ++e) s[e] -= lse;

    float cm[E_];
    #pragma unroll
    for (int e = 0; e < E_; ++e) {
      float v = s[e];
      for (int off = 32; off; off >>= 1) v = fmaxf(v, __shfl_xor(v, off));
      if (lane == 0) red[wid][e] = v;
    }
    __syncthreads();
    #pragma unroll
    for (int e = 0; e < E_; ++e) {
      float mm = red[0][e];
      for (int wv = 1; wv < 16; ++wv) mm = fmaxf(mm, red[wv][e]);
      cm[e] = mm;
    }
    __syncthreads();
    #pragma unroll
    for (int e = 0; e < E_; ++e) {
      float v = expf(s[e] - cm[e]);
      for (int off = 32; off; off >>= 1) v += __shfl_xor(v, off);
      if (lane == 0) red[wid][e] = v;
    }
    __syncthreads();
    #pragma unroll
    for (int e = 0; e < E_; ++e) {
      float ss = 0.f;
      for (int wv = 0; wv < 16; ++wv) ss += red[wv][e];
      s[e] -= cm[e] + logf(ss);
    }
    __syncthreads();
  }

  float g[E_]; float rs = 0.f;
  #pragma unroll
  for (int e = 0; e < E_; ++e) { g[e] = expf(s[e]); rs += g[e]; }
  float inv = 1.f / (rs + 1e-8f);
  #pragma unroll
  for (int e = 0; e < E_; ++e) g[e] *= inv;

  int i0 = 0; float v0 = g[0];
  #pragma unroll
  for (int e = 1; e < E_; ++e) if (g[e] > v0) { v0 = g[e]; i0 = e; }
  int i1 = -1; float v1 = -1e30f;
  #pragma unroll
  for (int e = 0; e < E_; ++e) if (e != i0 && g[e] > v1) { v1 = g[e]; i1 = e; }
  float den = 1.f / (v0 + v1 + 1e-8f);
  tkg[row * 2 + 0] = v0 * den; tki[row * 2 + 0] = i0;
  tkg[row * 2 + 1] = v1 * den; tki[row * 2 + 1] = i1;

  atomicAdd(&lcnt[i0], 1);
  atomicAdd(&lcnt[i1], 1);
  __syncthreads();
  if (t < E_) atomicAdd(&cnt[t], lcnt[t]);
}

__global__ void k_offsets(const int* __restrict__ cnt, int* __restrict__ segoff) {
  if (threadIdx.x == 0 && blockIdx.x == 0) {
    int run = 0;
    for (int e = 0; e < E_; ++e) { segoff[e] = run; run += ((cnt[e] + 127) >> 7) << 7; }
  }
}

__global__ __launch_bounds__(256) void k_scatter(const int* __restrict__ tki, const float* __restrict__ tkg,
                                                 const int* __restrict__ segoff, int* __restrict__ cur,
                                                 int* __restrict__ tok, float* __restrict__ gate) {
  int idx = blockIdx.x * 256 + threadIdx.x;    // 8192 pairs
  int row = idx >> 1;
  int e = tki[idx];
  float g = tkg[idx];
  int pos = atomicAdd(&cur[e], 1);
  int p = segoff[e] + pos;
  tok[p] = row;
  gate[p] = g;
}

// f32 [z][R][C] -> bf16 [z][C][R]
__global__ __launch_bounds__(256) void k_transpose(const float* __restrict__ in, u16* __restrict__ out,
                                                   int R, int C) {
  __shared__ __align__(16) u16 t[32][36];
  const size_t msz = (size_t)R * C;
  const float* A = in + blockIdx.z * msz;
  u16* O = out + blockIdx.z * msz;
  const int r0 = blockIdx.y * 32, c0 = blockIdx.x * 32;
  const int tid = threadIdx.x;
  {
    const int i = tid >> 3, j4 = (tid & 7) << 2;
    const float4 v = *(const float4*)(A + (size_t)(r0 + i) * C + c0 + j4);
    ushort4 pk; pk.x = f2bf(v.x); pk.y = f2bf(v.y); pk.z = f2bf(v.z); pk.w = f2bf(v.w);
    *(ushort4*)(&t[i][j4]) = pk;
  }
  __syncthreads();
  {
    const int j2 = tid & 15;
    #pragma unroll
    for (int it = 0; it < 2; ++it) {
      const int r = (tid >> 4) + it * 16;
      uint32_t pv = (uint32_t)t[2 * j2][r] | ((uint32_t)t[2 * j2 + 1][r] << 16);
      *(uint32_t*)(O + (size_t)(c0 + r) * R + r0 + 2 * j2) = pv;
    }
  }
}

// ---- GEMM LDS layout (per operand tile, BK=64): rowblocks of 16 rows.
// u16 offset = rowblock*1024 + kc*512 + lane*8, where kc in {0,1} is the
// 32-wide K chunk. Fragment read for (rowblock, kc) = single linear
// ds_read_b128 at rowblock*1024 + kc*512 + lane*8 -> conflict-free.
// gl_lds16 staging: wave w writes rowblock rb at dst base rb*1024 + r*512
// (r = kc round); lane i lands at +i*8 u16 = row (i&15), chunk (i>>4). The
// matching global source for lane i is row (i&15), k-offset r*32+(i>>4)*8.

// ---------------- stage 1: H = relu(X wg) * (X wp) ----------------
// Tile: 128 f x 128 p, BK=64, 16 K-tiles. 8 waves (512 thr): wave w ->
// f-half fw=w>>2 (64 f), p-quarter pw=w&3 (32 p). One barrier per K-tile;
// prefetch of tile t+1 issued right after the barrier (which proves all
// waves finished reading that buffer) -> race-free 2-buffer pipeline.
__global__ __launch_bounds__(512, 2) void k_stage1(
    const u16* __restrict__ wgT, const u16* __restrict__ wpT,
    const u16* __restrict__ xb, const int* __restrict__ tok,
    const int* __restrict__ cnt, const int* __restrict__ segoff,
    u16* __restrict__ H) {
  const int raw = blockIdx.x;
  const int e   = raw & 7;           // XCD pin
  const int rem = raw >> 3;          // 0..511
  const int ft  = rem >> 5;          // 0..15
  const int pt  = rem & 31;          // 0..31
  if (pt * 128 >= cnt[e]) return;
  const int tid = threadIdx.x;
  const int lane = tid & 63;
  const int w = tid >> 6;
  const int lane15 = lane & 15, lchunk = lane >> 4;
  const int fw = w >> 2, pw = w & 3;

  __shared__ __align__(16) u16 LG[2][8192];
  __shared__ __align__(16) u16 LP[2][8192];
  __shared__ __align__(16) u16 LX[2][8192];   // 96 KB total

  const int prow0 = segoff[e] + pt * 128;

  // staging sources: wave w stages rowblock w of each operand (2 kc rounds)
  const size_t wb = (size_t)e * FF_ * D_ + (size_t)(ft * 128 + w * 16 + lane15) * D_ + lchunk * 8;
  const u16* gsrc = wgT + wb;
  const u16* psrc = wpT + wb;
  const int tk = tok[prow0 + w * 16 + lane15];
  const u16* xsrc = xb + (size_t)tk * D_ + lchunk * 8;
  const int dstb = w * 1024;

  const f32x4 vz = {0.f, 0.f, 0.f, 0.f};
  f32x4 accG[4][2], accP[4][2];
  #pragma unroll
  for (int m = 0; m < 4; ++m)
    #pragma unroll
    for (int n = 0; n < 2; ++n) { accG[m][n] = vz; accP[m][n] = vz; }

#define ISSUE1(c, t) do { const int o_ = (t) * 64;                 \
    gl_lds16(gsrc + o_,      &LG[c][dstb]);                        \
    gl_lds16(gsrc + o_ + 32, &LG[c][dstb + 512]);                  \
    gl_lds16(psrc + o_,      &LP[c][dstb]);                        \
    gl_lds16(psrc + o_ + 32, &LP[c][dstb + 512]);                  \
    gl_lds16(xsrc + o_,      &LX[c][dstb]);                        \
    gl_lds16(xsrc + o_ + 32, &LX[c][dstb + 512]); } while (0)

  ISSUE1(0, 0);
  #pragma unroll 1
  for (int t = 0; t < NT1; ++t) {
    const int c = t & 1;
    __syncthreads();                  // drains vmcnt(0): tile t staged; buffer c^1 free
    if (t + 1 < NT1) ISSUE1(c ^ 1, t + 1);
    const u16* lg = LG[c];
    const u16* lp = LP[c];
    const u16* lx = LX[c];
    #pragma unroll
    for (int kc = 0; kc < 2; ++kc) {
      bf16x8 ag[4], ap[4], bx[2];
      #pragma unroll
      for (int m = 0; m < 4; ++m) {
        ag[m] = *(const bf16x8*)(lg + (fw * 4 + m) * 1024 + kc * 512 + lane * 8);
        ap[m] = *(const bf16x8*)(lp + (fw * 4 + m) * 1024 + kc * 512 + lane * 8);
      }
      #pragma unroll
      for (int n = 0; n < 2; ++n)
        bx[n] = *(const bf16x8*)(lx + (pw * 2 + n) * 1024 + kc * 512 + lane * 8);
      __builtin_amdgcn_s_setprio(1);
      #pragma unroll
      for (int m = 0; m < 4; ++m)
        #pragma unroll
        for (int n = 0; n < 2; ++n) {
          accG[m][n] = MFMA16(ag[m], bx[n], accG[m][n]);
          accP[m][n] = MFMA16(ap[m], bx[n], accP[m][n]);
        }
      __builtin_amdgcn_s_setprio(0);
    }
  }
#undef ISSUE1

  // epilogue: H[p][f], lane's 4 acc regs are consecutive f -> packed 8B stores
  const int jrow = lchunk * 4;
  #pragma unroll
  for (int m = 0; m < 4; ++m) {
    #pragma unroll
    for (int n = 0; n < 2; ++n) {
      union { uint2 v; u16 s[4]; } u;
      #pragma unroll
      for (int j = 0; j < 4; ++j)
        u.s[j] = f2bf(fmaxf(accG[m][n][j], 0.f) * accP[m][n][j]);
      const int prow = prow0 + pw * 32 + n * 16 + lane15;
      const int fcol = ft * 128 + fw * 64 + m * 16 + jrow;
      *(uint2*)(H + (size_t)prow * FF_ + fcol) = u.v;
    }
  }
}

// ---------------- stage 2: O = (H @ wo) * gate, atomic += into out ----------------
// Tile: 128 p x 256 d, BK=64, 32 K-tiles. 8 waves: p-half ph=w>>2 (64 p),
// d-quarter dq=w&3 (64 d). Same 2-buffer single-barrier pipeline.
__global__ __launch_bounds__(512, 2) void k_stage2(
    const u16* __restrict__ H, const u16* __restrict__ woT,
    const int* __restrict__ tok, const float* __restrict__ gate,
    const int* __restrict__ cnt, const int* __restrict__ segoff,
    float* __restrict__ out) {
  const int raw = blockIdx.x;
  const int e   = raw & 7;
  const int rem = raw >> 3;          // 0..127
  const int dt  = rem >> 5;          // 0..3
  const int pt  = rem & 31;          // 0..31
  if (pt * 128 >= cnt[e]) return;
  const int tid = threadIdx.x;
  const int lane = tid & 63;
  const int w = tid >> 6;
  const int lane15 = lane & 15, lchunk = lane >> 4;
  const int ph = w >> 2, dq = w & 3;

  __shared__ __align__(16) u16 LH[2][8192];
  __shared__ __align__(16) u16 LW[2][16384];  // 96 KB total
  __shared__ int   ltok[128];
  __shared__ float lgt[128];

  const int prow0 = segoff[e] + pt * 128;
  if (tid < 128) { ltok[tid] = tok[prow0 + tid]; lgt[tid] = gate[prow0 + tid]; }

  const u16* hsrc  = H + (size_t)(prow0 + w * 16 + lane15) * FF_ + lchunk * 8;
  const u16* wsrc0 = woT + (size_t)e * D_ * FF_ + (size_t)(dt * 256 + w * 16 + lane15) * FF_ + lchunk * 8;
  const u16* wsrc1 = wsrc0 + (size_t)128 * FF_;   // rowblock w+8
  const int dstb = w * 1024;

  const f32x4 vz = {0.f, 0.f, 0.f, 0.f};
  f32x4 acc[4][4];
  #pragma unroll
  for (int m = 0; m < 4; ++m)
    #pragma unroll
    for (int n = 0; n < 4; ++n) acc[m][n] = vz;

#define ISSUE2(c, t) do { const int o_ = (t) * 64;                 \
    gl_lds16(hsrc + o_,       &LH[c][dstb]);                       \
    gl_lds16(hsrc + o_ + 32,  &LH[c][dstb + 512]);                 \
    gl_lds16(wsrc0 + o_,      &LW[c][dstb]);                       \
    gl_lds16(wsrc0 + o_ + 32, &LW[c][dstb + 512]);                 \
    gl_lds16(wsrc1 + o_,      &LW[c][dstb + 8192]);                \
    gl_lds16(wsrc1 + o_ + 32, &LW[c][dstb + 8192 + 512]); } while (0)

  ISSUE2(0, 0);
  #pragma unroll 1
  for (int t = 0; t < NT2; ++t) {
    const int c = t & 1;
    __syncthreads();
    if (t + 1 < NT2) ISSUE2(c ^ 1, t + 1);
    const u16* lh = LH[c];
    const u16* lw = LW[c];
    #pragma unroll
    for (int kc = 0; kc < 2; ++kc) {
      bf16x8 ah[4], bw[4];
      #pragma unroll
      for (int m = 0; m < 4; ++m)
        ah[m] = *(const bf16x8*)(lh + (ph * 4 + m) * 1024 + kc * 512 + lane * 8);
      #pragma unroll
      for (int n = 0; n < 4; ++n)
        bw[n] = *(const bf16x8*)(lw + (dq * 4 + n) * 1024 + kc * 512 + lane * 8);
      __builtin_amdgcn_s_setprio(1);
      #pragma unroll
      for (int m = 0; m < 4; ++m)
        #pragma unroll
        for (int n = 0; n < 4; ++n)
          acc[m][n] = MFMA16(ah[m], bw[n], acc[m][n]);
      __builtin_amdgcn_s_setprio(0);
    }
  }
#undef ISSUE2

  const int jrow = lchunk * 4;
  #pragma unroll
  for (int m = 0; m < 4; ++m) {
    #pragma unroll
    for (int n = 0; n < 4; ++n) {
      const int dcol = dt * 256 + dq * 64 + n * 16 + lane15;
      #pragma unroll
      for (int j = 0; j < 4; ++j) {
        const int pl = ph * 64 + m * 16 + jrow + j;
        unsafeAtomicAdd(&out[(size_t)ltok[pl] * D_ + dcol], lgt[pl] * acc[m][n][j]);
      }
    }
  }
}

// ---------------- host ----------------

extern "C" void kernel_launch(void* const* d_in, const int* in_sizes, int n_in,
                              void* d_out, int out_size, void* d_ws, size_t ws_size,
                              hipStream_t stream) {
  const float* x    = (const float*)d_in[0];
  const float* rw   = (const float*)d_in[1];
  const float* rb   = (const float*)d_in[2];
  const float* temp = (const float*)d_in[3];
  const float* wg   = (const float*)d_in[4];
  const float* wp   = (const float*)d_in[5];
  const float* wo   = (const float*)d_in[6];
  float* out = (float*)d_out;
  char* ws = (char*)d_ws;

  // workspace layout (bytes)
  const size_t O_XB  = 0;                                  // NT*D bf16      = 8,388,608
  const size_t O_WGT = 8388608;                            // E*FF*D bf16    = 33,554,432
  const size_t O_WPT = O_WGT + 33554432;
  const size_t O_WOT = O_WGT;                              // reuses wgT region after stage1
  const size_t O_H   = O_WPT + 33554432;                   // LCAP*FF bf16   = 37,748,736
  const size_t O_SC  = O_H + (size_t)LCAP * FF_ * 2;
  const size_t O_TKG = O_SC + (size_t)NT_ * E_ * 4;
  const size_t O_TKI = O_TKG + (size_t)NT_ * 2 * 4;
  const size_t O_CNT = O_TKI + (size_t)NT_ * 2 * 4;
  const size_t O_CUR = O_CNT + 128;
  const size_t O_SEG = O_CUR + 128;
  const size_t O_TOK = O_SEG + 128;
  const size_t O_GTE = O_TOK + (size_t)LCAP * 4;
  const size_t REQ   = O_GTE + (size_t)LCAP * 4;           // ~108.3 MB
  if (ws_size < REQ) return;

  u16*   xb     = (u16*)(ws + O_XB);
  u16*   wgT    = (u16*)(ws + O_WGT);
  u16*   wpT    = (u16*)(ws + O_WPT);
  u16*   woT    = (u16*)(ws + O_WOT);
  u16*   Hbuf   = (u16*)(ws + O_H);
  float* scores = (float*)(ws + O_SC);
  float* tkg    = (float*)(ws + O_TKG);
  int*   tki    = (int*)(ws + O_TKI);
  int*   cnt    = (int*)(ws + O_CNT);
  int*   cur    = (int*)(ws + O_CUR);
  int*   segoff = (int*)(ws + O_SEG);
  int*   tok    = (int*)(ws + O_TOK);
  float* gate   = (float*)(ws + O_GTE);

  k_init<<<(LCAP + 255) / 256, 256, 0, stream>>>(tok, gate, cnt, cur);
  k_prep<<<(NT_ * D_ / 4) / 256, 256, 0, stream>>>((const float4*)x, (float4*)out, (ushort4*)xb);
  k_router<<<NT_ / 4, 256, 0, stream>>>(x, rw, rb, temp, scores);
  k_sinkhorn<<<B_, 1024, 0, stream>>>(scores, tkg, tki, cnt);
  k_offsets<<<1, 64, 0, stream>>>(cnt, segoff);
  k_scatter<<<(NT_ * 2) / 256, 256, 0, stream>>>(tki, tkg, segoff, cur, tok, gate);

  // weight transposes to bf16: wg,wp: [D][FF] -> [FF][D]
  k_transpose<<<dim3(FF_ / 32, D_ / 32, E_), 256, 0, stream>>>(wg, wgT, D_, FF_);
  k_transpose<<<dim3(FF_ / 32, D_ / 32, E_), 256, 0, stream>>>(wp, wpT, D_, FF_);

  k_stage1<<<32 * 16 * E_, 512, 0, stream>>>(wgT, wpT, xb, tok, cnt, segoff, Hbuf);

  // wo: [FF][D] -> [D][FF]  (overwrites wgT region, dead after stage1)
  k_transpose<<<dim3(D_ / 32, FF_ / 32, E_), 256, 0, stream>>>(wo, woT, FF_, D_);

  k_stage2<<<32 * 4 * E_, 512, 0, stream>>>(Hbuf, woT, tok, gate, cnt, segoff, out);
}

// Round 4
// 473.807 us; speedup vs baseline: 1.8406x; 1.1409x over previous
//
#include <hip/hip_runtime.h>
#include <hip/hip_bf16.h>
#include <stdint.h>

// Problem constants
#define B_   4
#define T_   1024
#define D_   1024
#define E_   8
#define FF_  2048
#define NT_  4096            // B*T tokens
#define LCAP 9216            // 8192 pairs + 8*128 tile padding headroom
#define NT1  (D_ / 32)       // 32 K-tiles, stage1 (BK=32)
#define NT2  (FF_ / 32)      // 64 K-tiles, stage2 (BK=32)

typedef unsigned short u16;
typedef __attribute__((ext_vector_type(8))) short bf16x8;   // 8 bf16 = 4 VGPRs
typedef __attribute__((ext_vector_type(4))) float f32x4;

#define MFMA16(a, b, c) __builtin_amdgcn_mfma_f32_16x16x32_bf16((a), (b), (c), 0, 0, 0)

__device__ __forceinline__ u16 f2bf(float f) {
  union { float f; uint32_t u; } c; c.f = f;
  return (u16)((c.u + 0x7FFFu + ((c.u >> 16) & 1u)) >> 16);   // RNE
}

__device__ __forceinline__ void gl_lds16(const void* g, void* l) {
  __builtin_amdgcn_global_load_lds(
      (const __attribute__((address_space(1))) uint32_t*)g,
      (__attribute__((address_space(3))) uint32_t*)l, 16, 0, 0);
}

// ---------------- small kernels ----------------

__global__ __launch_bounds__(256) void k_init(int* __restrict__ tok, float* __restrict__ gate,
                                              int* __restrict__ cnt, int* __restrict__ cur) {
  int i = blockIdx.x * 256 + threadIdx.x;
  if (i < LCAP) { tok[i] = 0; gate[i] = 0.f; }
  if (i < E_)   { cnt[i] = 0; cur[i] = 0; }
}

// out = x (f32 copy) and xb = bf16(x), one pass over x
__global__ __launch_bounds__(256) void k_prep(const float4* __restrict__ x4,
                                              float4* __restrict__ out4,
                                              ushort4* __restrict__ xb4) {
  int i = blockIdx.x * 256 + threadIdx.x;   // exactly NT_*D_/4 threads
  float4 v = x4[i];
  out4[i] = v;
  ushort4 o; o.x = f2bf(v.x); o.y = f2bf(v.y); o.z = f2bf(v.z); o.w = f2bf(v.w);
  xb4[i] = o;
}

// one wave per token: 8 dot products of length 1024
__global__ __launch_bounds__(256) void k_router(const float* __restrict__ x,
                                                const float* __restrict__ rw,
                                                const float* __restrict__ rb,
                                                const float* __restrict__ temp,
                                                float* __restrict__ scores) {
  int wid  = (blockIdx.x * 256 + threadIdx.x) >> 6;   // token id
  int lane = threadIdx.x & 63;
  const float* xr = x + (size_t)wid * D_;
  float acc[E_];
  #pragma unroll
  for (int e = 0; e < E_; ++e) acc[e] = 0.f;
  for (int i = lane; i < D_; i += 64) {
    float xv = xr[i];
    #pragma unroll
    for (int e = 0; e < E_; ++e) acc[e] += xv * rw[e * D_ + i];
  }
  float inv = 1.0f / fmaxf(temp[0], 0.1f);
  #pragma unroll
  for (int e = 0; e < E_; ++e) {
    float v = acc[e];
    for (int off = 32; off; off >>= 1) v += __shfl_xor(v, off);
    if (lane == 0) scores[(size_t)wid * E_ + e] = (v + rb[e]) * inv;
  }
}

// one block per batch b; thread t owns token row [b,t]; 3 Sinkhorn iters + top-2
__global__ __launch_bounds__(1024) void k_sinkhorn(const float* __restrict__ scores,
                                                   float* __restrict__ tkg, int* __restrict__ tki,
                                                   int* __restrict__ cnt) {
  const int b = blockIdx.x, t = threadIdx.x;
  const int row = b * T_ + t;
  float s[E_];
  #pragma unroll
  for (int e = 0; e < E_; ++e) s[e] = scores[(size_t)row * E_ + e];

  __shared__ float red[16][E_];
  __shared__ int lcnt[E_];
  if (t < E_) lcnt[t] = 0;
  const int wid = t >> 6, lane = t & 63;

  for (int it = 0; it < 3; ++it) {
    float m = s[0];
    #pragma unroll
    for (int e = 1; e < E_; ++e) m = fmaxf(m, s[e]);
    float sum = 0.f;
    #pragma unroll
    for (int e = 0; e < E_; ++e) sum += expf(s[e] - m);
    float lse = m + logf(sum);
    #pragma unroll
    for (int e = 0; e < E_; ++e) s[e] -= lse;

    float cm[E_];
    #pragma unroll
    for (int e = 0; e < E_; ++e) {
      float v = s[e];
      for (int off = 32; off; off >>= 1) v = fmaxf(v, __shfl_xor(v, off));
      if (lane == 0) red[wid][e] = v;
    }
    __syncthreads();
    #pragma unroll
    for (int e = 0; e < E_; ++e) {
      float mm = red[0][e];
      for (int wv = 1; wv < 16; ++wv) mm = fmaxf(mm, red[wv][e]);
      cm[e] = mm;
    }
    __syncthreads();
    #pragma unroll
    for (int e = 0; e < E_; ++e) {
      float v = expf(s[e] - cm[e]);
      for (int off = 32; off; off >>= 1) v += __shfl_xor(v, off);
      if (lane == 0) red[wid][e] = v;
    }
    __syncthreads();
    #pragma unroll
    for (int e = 0; e < E_; ++e) {
      float ss = 0.f;
      for (int wv = 0; wv < 16; ++wv) ss += red[wv][e];
      s[e] -= cm[e] + logf(ss);
    }
    __syncthreads();
  }

  float g[E_]; float rs = 0.f;
  #pragma unroll
  for (int e = 0; e < E_; ++e) { g[e] = expf(s[e]); rs += g[e]; }
  float inv = 1.f / (rs + 1e-8f);
  #pragma unroll
  for (int e = 0; e < E_; ++e) g[e] *= inv;

  int i0 = 0; float v0 = g[0];
  #pragma unroll
  for (int e = 1; e < E_; ++e) if (g[e] > v0) { v0 = g[e]; i0 = e; }
  int i1 = -1; float v1 = -1e30f;
  #pragma unroll
  for (int e = 0; e < E_; ++e) if (e != i0 && g[e] > v1) { v1 = g[e]; i1 = e; }
  float den = 1.f / (v0 + v1 + 1e-8f);
  tkg[row * 2 + 0] = v0 * den; tki[row * 2 + 0] = i0;
  tkg[row * 2 + 1] = v1 * den; tki[row * 2 + 1] = i1;

  atomicAdd(&lcnt[i0], 1);
  atomicAdd(&lcnt[i1], 1);
  __syncthreads();
  if (t < E_) atomicAdd(&cnt[t], lcnt[t]);
}

__global__ void k_offsets(const int* __restrict__ cnt, int* __restrict__ segoff) {
  if (threadIdx.x == 0 && blockIdx.x == 0) {
    int run = 0;
    for (int e = 0; e < E_; ++e) { segoff[e] = run; run += ((cnt[e] + 127) >> 7) << 7; }
  }
}

__global__ __launch_bounds__(256) void k_scatter(const int* __restrict__ tki, const float* __restrict__ tkg,
                                                 const int* __restrict__ segoff, int* __restrict__ cur,
                                                 int* __restrict__ tok, float* __restrict__ gate) {
  int idx = blockIdx.x * 256 + threadIdx.x;    // 8192 pairs
  int row = idx >> 1;
  int e = tki[idx];
  float g = tkg[idx];
  int pos = atomicAdd(&cur[e], 1);
  int p = segoff[e] + pos;
  tok[p] = row;
  gate[p] = g;
}

// f32 [z][R][C] -> bf16 [z][C][R]
__global__ __launch_bounds__(256) void k_transpose(const float* __restrict__ in, u16* __restrict__ out,
                                                   int R, int C) {
  __shared__ __align__(16) u16 t[32][36];
  const size_t msz = (size_t)R * C;
  const float* A = in + blockIdx.z * msz;
  u16* O = out + blockIdx.z * msz;
  const int r0 = blockIdx.y * 32, c0 = blockIdx.x * 32;
  const int tid = threadIdx.x;
  {
    const int i = tid >> 3, j4 = (tid & 7) << 2;
    const float4 v = *(const float4*)(A + (size_t)(r0 + i) * C + c0 + j4);
    ushort4 pk; pk.x = f2bf(v.x); pk.y = f2bf(v.y); pk.z = f2bf(v.z); pk.w = f2bf(v.w);
    *(ushort4*)(&t[i][j4]) = pk;
  }
  __syncthreads();
  {
    const int j2 = tid & 15;
    #pragma unroll
    for (int it = 0; it < 2; ++it) {
      const int r = (tid >> 4) + it * 16;
      uint32_t pv = (uint32_t)t[2 * j2][r] | ((uint32_t)t[2 * j2 + 1][r] << 16);
      *(uint32_t*)(O + (size_t)(c0 + r) * R + r0 + 2 * j2) = pv;
    }
  }
}

// ---- GEMM LDS layout (per operand tile, BK=32): 16-row rowblocks of 512 u16.
// u16 offset = rowblock*512 + lane*8; lane i holds row (i&15), k-chunk (i>>4).
// Fragment read = single linear ds_read_b128 (conflict-free); gl_lds16 staging
// writes lane i at +16i B, matching global src row (i&15), k-off (i>>4)*8.
//
// Pipeline (T3/T4): 3 buffers, depth-2 prefetch, one barrier per tile,
// per-wave counted s_waitcnt vmcnt(3) (= the 3 loads of tile t+1 stay in
// flight). ISSUE(t+2) goes to buffer (t-1)%3 whose readers all passed the
// barrier -> WAR-safe. Last tile peeled with vmcnt(0).

// ---------------- stage 1: H = relu(X wg) * (X wp) ----------------
// Tile: 128 f x 128 p, 8 waves: fw=w>>2 (64 f), pw=w&3 (32 p).
__global__ __launch_bounds__(512, 4) void k_stage1(
    const u16* __restrict__ wgT, const u16* __restrict__ wpT,
    const u16* __restrict__ xb, const int* __restrict__ tok,
    const int* __restrict__ cnt, const int* __restrict__ segoff,
    u16* __restrict__ H) {
  const int raw = blockIdx.x;
  const int e   = raw & 7;           // XCD pin
  const int rem = raw >> 3;
  const int ft  = rem >> 5;          // 0..15
  const int pt  = rem & 31;          // 0..31
  if (pt * 128 >= cnt[e]) return;
  const int tid = threadIdx.x;
  const int lane = tid & 63;
  const int w = tid >> 6;
  const int lane15 = lane & 15, lchunk = lane >> 4;
  const int fw = w >> 2, pw = w & 3;

  __shared__ __align__(16) u16 LG[3][4096];
  __shared__ __align__(16) u16 LP[3][4096];
  __shared__ __align__(16) u16 LX[3][4096];   // 72 KB -> 2 blocks/CU

  const int prow0 = segoff[e] + pt * 128;
  const size_t wb = (size_t)e * FF_ * D_ + (size_t)(ft * 128 + w * 16 + lane15) * D_ + lchunk * 8;
  const u16* gsrc = wgT + wb;
  const u16* psrc = wpT + wb;
  const int tk = tok[prow0 + w * 16 + lane15];
  const u16* xsrc = xb + (size_t)tk * D_ + lchunk * 8;
  const int dstb = w * 512;

  const f32x4 vz = {0.f, 0.f, 0.f, 0.f};
  f32x4 accG[4][2], accP[4][2];
  #pragma unroll
  for (int m = 0; m < 4; ++m)
    #pragma unroll
    for (int n = 0; n < 2; ++n) { accG[m][n] = vz; accP[m][n] = vz; }

#define ISSUE1(c, t) do { const int o_ = (t) * 32;                 \
    gl_lds16(gsrc + o_, &LG[c][dstb]);                             \
    gl_lds16(psrc + o_, &LP[c][dstb]);                             \
    gl_lds16(xsrc + o_, &LX[c][dstb]); } while (0)

#define COMP1(c) do {                                                        \
    const u16* lg = LG[c]; const u16* lp = LP[c]; const u16* lx = LX[c];     \
    bf16x8 ag[4], ap[4], bx[2];                                              \
    _Pragma("unroll")                                                        \
    for (int m = 0; m < 4; ++m) {                                            \
      ag[m] = *(const bf16x8*)(lg + (fw * 4 + m) * 512 + lane * 8);          \
      ap[m] = *(const bf16x8*)(lp + (fw * 4 + m) * 512 + lane * 8);          \
    }                                                                        \
    _Pragma("unroll")                                                        \
    for (int n = 0; n < 2; ++n)                                              \
      bx[n] = *(const bf16x8*)(lx + (pw * 2 + n) * 512 + lane * 8);          \
    __builtin_amdgcn_s_setprio(1);                                           \
    _Pragma("unroll")                                                        \
    for (int m = 0; m < 4; ++m)                                              \
      _Pragma("unroll")                                                      \
      for (int n = 0; n < 2; ++n) {                                          \
        accG[m][n] = MFMA16(ag[m], bx[n], accG[m][n]);                       \
        accP[m][n] = MFMA16(ap[m], bx[n], accP[m][n]);                       \
      }                                                                      \
    __builtin_amdgcn_s_setprio(0); } while (0)

  ISSUE1(0, 0);
  ISSUE1(1, 1);
  #pragma unroll 1
  for (int t = 0; t < NT1 - 1; ++t) {
    asm volatile("s_waitcnt vmcnt(3)" ::: "memory");   // tile t staged (ours)
    __builtin_amdgcn_s_barrier();                      // all waves' tile t staged
    asm volatile("" ::: "memory");
    if (t + 2 < NT1) { const int cn = (t + 2) % 3; ISSUE1(cn, t + 2); }
    const int c = t % 3;
    COMP1(c);
  }
  asm volatile("s_waitcnt vmcnt(0)" ::: "memory");
  __builtin_amdgcn_s_barrier();
  asm volatile("" ::: "memory");
  COMP1((NT1 - 1) % 3);
#undef ISSUE1
#undef COMP1

  // epilogue: H[p][f], lane's 4 acc regs are consecutive f -> packed 8B stores
  const int jrow = lchunk * 4;
  #pragma unroll
  for (int m = 0; m < 4; ++m) {
    #pragma unroll
    for (int n = 0; n < 2; ++n) {
      union { uint2 v; u16 s[4]; } u;
      #pragma unroll
      for (int j = 0; j < 4; ++j)
        u.s[j] = f2bf(fmaxf(accG[m][n][j], 0.f) * accP[m][n][j]);
      const int prow = prow0 + pw * 32 + n * 16 + lane15;
      const int fcol = ft * 128 + fw * 64 + m * 16 + jrow;
      *(uint2*)(H + (size_t)prow * FF_ + fcol) = u.v;
    }
  }
}

// ---------------- stage 2: O = (H @ wo) * gate, atomic += into out ----------------
// Tile: 128 p x 256 d, 8 waves: ph=w>>2 (64 p), dq=w&3 (64 d).
__global__ __launch_bounds__(512, 4) void k_stage2(
    const u16* __restrict__ H, const u16* __restrict__ woT,
    const int* __restrict__ tok, const float* __restrict__ gate,
    const int* __restrict__ cnt, const int* __restrict__ segoff,
    float* __restrict__ out) {
  const int raw = blockIdx.x;
  const int e   = raw & 7;
  const int rem = raw >> 3;          // 0..127
  const int dt  = rem >> 5;          // 0..3
  const int pt  = rem & 31;          // 0..31
  if (pt * 128 >= cnt[e]) return;
  const int tid = threadIdx.x;
  const int lane = tid & 63;
  const int w = tid >> 6;
  const int lane15 = lane & 15, lchunk = lane >> 4;
  const int ph = w >> 2, dq = w & 3;

  __shared__ __align__(16) u16 LH[3][4096];
  __shared__ __align__(16) u16 LW[3][8192];   // 72 KB -> 2 blocks/CU
  __shared__ int   ltok[128];
  __shared__ float lgt[128];

  const int prow0 = segoff[e] + pt * 128;
  if (tid < 128) { ltok[tid] = tok[prow0 + tid]; lgt[tid] = gate[prow0 + tid]; }

  const u16* hsrc  = H + (size_t)(prow0 + w * 16 + lane15) * FF_ + lchunk * 8;
  const u16* wsrc0 = woT + (size_t)e * D_ * FF_ + (size_t)(dt * 256 + w * 16 + lane15) * FF_ + lchunk * 8;
  const u16* wsrc1 = wsrc0 + (size_t)128 * FF_;   // rowblock w+8
  const int dstb = w * 512;

  const f32x4 vz = {0.f, 0.f, 0.f, 0.f};
  f32x4 acc[4][4];
  #pragma unroll
  for (int m = 0; m < 4; ++m)
    #pragma unroll
    for (int n = 0; n < 4; ++n) acc[m][n] = vz;

#define ISSUE2(c, t) do { const int o_ = (t) * 32;                 \
    gl_lds16(hsrc + o_,  &LH[c][dstb]);                            \
    gl_lds16(wsrc0 + o_, &LW[c][dstb]);                            \
    gl_lds16(wsrc1 + o_, &LW[c][dstb + 4096]); } while (0)

#define COMP2(c) do {                                                        \
    const u16* lh = LH[c]; const u16* lw = LW[c];                            \
    bf16x8 ah[4], bw[4];                                                     \
    _Pragma("unroll")                                                        \
    for (int m = 0; m < 4; ++m)                                              \
      ah[m] = *(const bf16x8*)(lh + (ph * 4 + m) * 512 + lane * 8);          \
    _Pragma("unroll")                                                        \
    for (int n = 0; n < 4; ++n)                                              \
      bw[n] = *(const bf16x8*)(lw + (dq * 4 + n) * 512 + lane * 8);          \
    __builtin_amdgcn_s_setprio(1);                                           \
    _Pragma("unroll")                                                        \
    for (int m = 0; m < 4; ++m)                                              \
      _Pragma("unroll")                                                      \
      for (int n = 0; n < 4; ++n)                                            \
        acc[m][n] = MFMA16(ah[m], bw[n], acc[m][n]);                         \
    __builtin_amdgcn_s_setprio(0); } while (0)

  ISSUE2(0, 0);
  ISSUE2(1, 1);
  #pragma unroll 1
  for (int t = 0; t < NT2 - 1; ++t) {
    asm volatile("s_waitcnt vmcnt(3)" ::: "memory");
    __builtin_amdgcn_s_barrier();
    asm volatile("" ::: "memory");
    if (t + 2 < NT2) { const int cn = (t + 2) % 3; ISSUE2(cn, t + 2); }
    const int c = t % 3;
    COMP2(c);
  }
  asm volatile("s_waitcnt vmcnt(0)" ::: "memory");
  __builtin_amdgcn_s_barrier();
  asm volatile("" ::: "memory");
  COMP2((NT2 - 1) % 3);
#undef ISSUE2
#undef COMP2

  const int jrow = lchunk * 4;
  #pragma unroll
  for (int m = 0; m < 4; ++m) {
    #pragma unroll
    for (int n = 0; n < 4; ++n) {
      const int dcol = dt * 256 + dq * 64 + n * 16 + lane15;
      #pragma unroll
      for (int j = 0; j < 4; ++j) {
        const int pl = ph * 64 + m * 16 + jrow + j;
        unsafeAtomicAdd(&out[(size_t)ltok[pl] * D_ + dcol], lgt[pl] * acc[m][n][j]);
      }
    }
  }
}

// ---------------- host ----------------

extern "C" void kernel_launch(void* const* d_in, const int* in_sizes, int n_in,
                              void* d_out, int out_size, void* d_ws, size_t ws_size,
                              hipStream_t stream) {
  const float* x    = (const float*)d_in[0];
  const float* rw   = (const float*)d_in[1];
  const float* rb   = (const float*)d_in[2];
  const float* temp = (const float*)d_in[3];
  const float* wg   = (const float*)d_in[4];
  const float* wp   = (const float*)d_in[5];
  const float* wo   = (const float*)d_in[6];
  float* out = (float*)d_out;
  char* ws = (char*)d_ws;

  // workspace layout (bytes)
  const size_t O_XB  = 0;                                  // NT*D bf16      = 8,388,608
  const size_t O_WGT = 8388608;                            // E*FF*D bf16    = 33,554,432
  const size_t O_WPT = O_WGT + 33554432;
  const size_t O_WOT = O_WGT;                              // reuses wgT region after stage1
  const size_t O_H   = O_WPT + 33554432;                   // LCAP*FF bf16   = 37,748,736
  const size_t O_SC  = O_H + (size_t)LCAP * FF_ * 2;
  const size_t O_TKG = O_SC + (size_t)NT_ * E_ * 4;
  const size_t O_TKI = O_TKG + (size_t)NT_ * 2 * 4;
  const size_t O_CNT = O_TKI + (size_t)NT_ * 2 * 4;
  const size_t O_CUR = O_CNT + 128;
  const size_t O_SEG = O_CUR + 128;
  const size_t O_TOK = O_SEG + 128;
  const size_t O_GTE = O_TOK + (size_t)LCAP * 4;
  const size_t REQ   = O_GTE + (size_t)LCAP * 4;           // ~108.3 MB
  if (ws_size < REQ) return;

  u16*   xb     = (u16*)(ws + O_XB);
  u16*   wgT    = (u16*)(ws + O_WGT);
  u16*   wpT    = (u16*)(ws + O_WPT);
  u16*   woT    = (u16*)(ws + O_WOT);
  u16*   Hbuf   = (u16*)(ws + O_H);
  float* scores = (float*)(ws + O_SC);
  float* tkg    = (float*)(ws + O_TKG);
  int*   tki    = (int*)(ws + O_TKI);
  int*   cnt    = (int*)(ws + O_CNT);
  int*   cur    = (int*)(ws + O_CUR);
  int*   segoff = (int*)(ws + O_SEG);
  int*   tok    = (int*)(ws + O_TOK);
  float* gate   = (float*)(ws + O_GTE);

  k_init<<<(LCAP + 255) / 256, 256, 0, stream>>>(tok, gate, cnt, cur);
  k_prep<<<(NT_ * D_ / 4) / 256, 256, 0, stream>>>((const float4*)x, (float4*)out, (ushort4*)xb);
  k_router<<<NT_ / 4, 256, 0, stream>>>(x, rw, rb, temp, scores);
  k_sinkhorn<<<B_, 1024, 0, stream>>>(scores, tkg, tki, cnt);
  k_offsets<<<1, 64, 0, stream>>>(cnt, segoff);
  k_scatter<<<(NT_ * 2) / 256, 256, 0, stream>>>(tki, tkg, segoff, cur, tok, gate);

  // weight transposes to bf16: wg,wp: [D][FF] -> [FF][D]
  k_transpose<<<dim3(FF_ / 32, D_ / 32, E_), 256, 0, stream>>>(wg, wgT, D_, FF_);
  k_transpose<<<dim3(FF_ / 32, D_ / 32, E_), 256, 0, stream>>>(wp, wpT, D_, FF_);

  k_stage1<<<32 * 16 * E_, 512, 0, stream>>>(wgT, wpT, xb, tok, cnt, segoff, Hbuf);

  // wo: [FF][D] -> [D][FF]  (overwrites wgT region, dead after stage1)
  k_transpose<<<dim3(D_ / 32, FF_ / 32, E_), 256, 0, stream>>>(wo, woT, FF_, D_);

  k_stage2<<<32 * 4 * E_, 512, 0, stream>>>(Hbuf, woT, tok, gate, cnt, segoff, out);
}